// Round 7
// baseline (615.779 us; speedup 1.0000x reference)
//
#include <hip/hip_runtime.h>

#define NNODES 50000
#define HEADS 3
#define NBUCK 196          // ceil(50000/256)
#define BCAP  16320        // per-bucket edge capacity (avg 8163)

typedef __attribute__((ext_vector_type(8))) short bf16x8;
typedef __attribute__((ext_vector_type(4))) float f32x4;

__device__ __forceinline__ float wred_sum(float v){
  #pragma unroll
  for (int s = 32; s > 0; s >>= 1) v += __shfl_xor(v, s, 64);
  return v;
}
__device__ __forceinline__ unsigned short f2bf(float x){
  unsigned int u = __float_as_uint(x);
  unsigned int r = (u + 0x7FFFu + ((u >> 16) & 1u)) >> 16;
  return (unsigned short)r;
}

// ---------------- x (fp32) -> bf16, vectorized ----------------
__global__ __launch_bounds__(256) void cvt_bf16_kernel(
    const float* __restrict__ in, unsigned short* __restrict__ outb, int n4)
{
  int i = blockIdx.x * 256 + threadIdx.x;
  if (i >= n4) return;
  float4 v = ((const float4*)in)[i];
  ushort4 o;
  o.x = f2bf(v.x); o.y = f2bf(v.y); o.z = f2bf(v.z); o.w = f2bf(v.w);
  ((ushort4*)outb)[i] = o;
}

// ---------------- W -> MFMA-fragment bf16, with folded el/er columns -------
__global__ __launch_bounds__(256) void prep_b_kernel(
    const float* __restrict__ W, const float* __restrict__ al,
    const float* __restrict__ ar, unsigned short* __restrict__ Bf,
    int K, int NT, int NCf, int F)
{
  int tid = blockIdx.x * 256 + threadIdx.x;
  int total = (K >> 5) * NT * 64;
  if (tid >= total) return;
  int l  = tid & 63;
  int t  = (tid >> 6) % NT;
  int kc = tid / (NT * 64);
  int k0  = kc * 32 + (l >> 4) * 8;
  int col = t * 16 + (l & 15);
  unsigned short o[8];
  #pragma unroll
  for (int j = 0; j < 8; ++j) {
    int k = k0 + j;
    float v = 0.f;
    if (col < NCf) {
      v = W[(size_t)k * NCf + col];
    } else if (col < NCf + 6) {
      int c = col - NCf;
      int h = (c < 3) ? c : c - 3;
      const float* av = ((c < 3) ? al : ar) + h * F;
      const float* wp = W + (size_t)k * NCf + h * F;
      float a = 0.f;
      for (int f = 0; f < F; ++f) a += wp[f] * av[f];
      v = a;
    }
    o[j] = f2bf(v);
  }
  ushort4* dst = (ushort4*)&Bf[(size_t)tid * 8];
  dst[0] = make_ushort4(o[0], o[1], o[2], o[3]);
  dst[1] = make_ushort4(o[4], o[5], o[6], o[7]);
}

// ---------------- MFMA GEMM + el/er epilogue ----------------
// A addressing: elem = hblk*HS + row*NS + (k&63)  (hblk = k>>6)
//   xb (node-major [N][256]) : HS=64,    NS=256
//   aggb (head-major [h][N][64]): HS=N*64, NS=64
// C written HEAD-MAJOR: featb[h][N][FH], h = c/FH.
__global__ __launch_bounds__(256) void gemm_mfma_kernel(
    const unsigned short* __restrict__ Ab, const unsigned short* __restrict__ Bf,
    unsigned short* __restrict__ Cb, float* __restrict__ elp, float* __restrict__ erp,
    int M, int K, int NT, int NCf, unsigned long long HS, int NS, int FH)
{
  const int w = threadIdx.x >> 6, l = threadIdx.x & 63;
  const int lrow = l & 15, kg = l >> 4;
  const int r0 = blockIdx.x * 64;
  const bf16x8* Bfv = (const bf16x8*)Bf;

  f32x4 acc[4][4];
  #pragma unroll
  for (int mt = 0; mt < 4; ++mt)
    #pragma unroll
    for (int j = 0; j < 4; ++j)
      acc[mt][j] = (f32x4){0.f, 0.f, 0.f, 0.f};

  const int nkc = K >> 5;
  for (int kc = 0; kc < nkc; ++kc) {
    const size_t abase = (size_t)(kc >> 1) * HS + (size_t)((kc & 1) * 32 + kg * 8);
    bf16x8 af[4];
    #pragma unroll
    for (int mt = 0; mt < 4; ++mt) {
      int row = r0 + mt * 16 + lrow;
      bf16x8 z = {0,0,0,0,0,0,0,0};
      af[mt] = z;
      if (row < M)
        af[mt] = *(const bf16x8*)&Ab[abase + (size_t)row * NS];
    }
    #pragma unroll
    for (int j = 0; j < 4; ++j) {
      int tile = w + 4 * j;
      if (tile < NT) {
        bf16x8 bfr = Bfv[((size_t)kc * NT + tile) * 64 + l];
        #pragma unroll
        for (int mt = 0; mt < 4; ++mt)
          acc[mt][j] = __builtin_amdgcn_mfma_f32_16x16x32_bf16(af[mt], bfr, acc[mt][j], 0, 0, 0);
      }
    }
  }
  #pragma unroll
  for (int j = 0; j < 4; ++j) {
    int tile = w + 4 * j;
    if (tile >= NT) continue;
    int c = tile * 16 + lrow;
    int hh = 0, ff = 0;
    if (c < NCf) { hh = c / FH; ff = c - hh * FH; }
    #pragma unroll
    for (int mt = 0; mt < 4; ++mt) {
      #pragma unroll
      for (int rr = 0; rr < 4; ++rr) {
        int row = r0 + mt * 16 + kg * 4 + rr;
        if (row >= M) continue;
        float v = acc[mt][j][rr];
        if (c < NCf)            Cb[(size_t)hh * M * FH + (size_t)row * FH + ff] = f2bf(v);
        else if (c < NCf + 3)   elp[row * 4 + (c - NCf)] = v;
        else if (c < NCf + 6)   erp[row * 4 + (c - NCf - 3)] = v;
      }
    }
  }
}

// ---------------- CSR build: bucket partition ----------------
__global__ __launch_bounds__(256) void partition_kernel(
    const int* __restrict__ src, const int* __restrict__ dst,
    int* __restrict__ bcur, uint2* __restrict__ ebuf, int E)
{
  __shared__ int hist[NBUCK];
  __shared__ int gbase[NBUCK];
  const int t = threadIdx.x;
  const int e0 = blockIdx.x * 2048;
  for (int i = t; i < NBUCK; i += 256) hist[i] = 0;
  __syncthreads();
  int  b_[8], r_[8];
  uint2 p_[8];
  #pragma unroll
  for (int v = 0; v < 8; ++v) {
    int e = e0 + v * 256 + t;
    b_[v] = -1;
    if (e < E) {
      int s = src[e], d = dst[e];
      p_[v] = make_uint2((unsigned)s, (unsigned)d);
      b_[v] = d >> 8;
      r_[v] = atomicAdd(&hist[b_[v]], 1);
    }
  }
  __syncthreads();
  for (int i = t; i < NBUCK; i += 256) {
    int h = hist[i];
    gbase[i] = h ? atomicAdd(&bcur[i], h) : 0;
  }
  __syncthreads();
  #pragma unroll
  for (int v = 0; v < 8; ++v)
    if (b_[v] >= 0)
      ebuf[(size_t)b_[v] * BCAP + gbase[b_[v]] + r_[v]] = p_[v];
}

__global__ __launch_bounds__(256) void bucket_scan_kernel(
    const int* __restrict__ bcur, int* __restrict__ bbase)
{
  __shared__ int wsum[4];
  int t = threadIdx.x, wv = t >> 6, l = t & 63;
  int v = (t < NBUCK) ? bcur[t] : 0;
  int x = v;
  #pragma unroll
  for (int s = 1; s < 64; s <<= 1) {
    int y = __shfl_up(x, s, 64);
    if (l >= s) x += y;
  }
  if (l == 63) wsum[wv] = x;
  __syncthreads();
  int woff = 0;
  #pragma unroll
  for (int k = 0; k < 4; ++k) woff += (k < wv) ? wsum[k] : 0;
  if (t < NBUCK) bbase[t] = woff + x - v;
}

__global__ __launch_bounds__(256) void fill_local_kernel(
    const uint2* __restrict__ ebuf, const int* __restrict__ bcur,
    const int* __restrict__ bbase, int* __restrict__ off,
    int* __restrict__ adj, int N)
{
  __shared__ int lhist[256], loff[256], lcur[256];
  __shared__ int wsum[4];
  const int b = blockIdx.x;
  const int t = threadIdx.x;
  const int cnt  = bcur[b];
  const int base = bbase[b];
  const uint2* seg = ebuf + (size_t)b * BCAP;
  lhist[t] = 0; lcur[t] = 0;
  __syncthreads();
  for (int i = t; i < cnt; i += 256)
    atomicAdd(&lhist[seg[i].y & 255], 1);
  __syncthreads();
  int wv = t >> 6, l = t & 63;
  int v = lhist[t];
  int x = v;
  #pragma unroll
  for (int s = 1; s < 64; s <<= 1) {
    int y = __shfl_up(x, s, 64);
    if (l >= s) x += y;
  }
  if (l == 63) wsum[wv] = x;
  __syncthreads();
  int woff = 0;
  #pragma unroll
  for (int k = 0; k < 4; ++k) woff += (k < wv) ? wsum[k] : 0;
  loff[t] = woff + x - v;
  int gd = (b << 8) + t;
  if (gd <= N) off[gd] = base + loff[t];
  __syncthreads();
  for (int i = t; i < cnt; i += 256) {
    uint2 p = seg[i];
    int d = p.y & 255;
    int r = atomicAdd(&lcur[d], 1);
    adj[base + loff[d] + r] = (int)p.x;
  }
}

// ---------------- aggregation: wave/node, flash softmax, head-phased ------
// featb is HEAD-MAJOR [h][N][F] bf16. All waves sweep h=0,1,2 in order so the
// instantaneous gather working set is one 6.4MB (or 4MB) head table.
// mode 0: out = relu(agg) -> bf16 head-major [h][N][64]
// mode 1: out = mean over heads -> fp32 node-major [N,40]
__global__ __launch_bounds__(256) void aggregate_kernel(
    const unsigned short* __restrict__ featb, const int* __restrict__ adj,
    const int* __restrict__ off, const float* __restrict__ elp,
    const float* __restrict__ erp, void* __restrict__ outp,
    int N, int F, int mode)
{
  __shared__ float4 pl[4][68];
  int wv = threadIdx.x >> 6, l = threadIdx.x & 63;
  int n  = blockIdx.x * 4 + wv;
  if (n >= N) return;
  const int G  = (F == 64) ? 16 : 10;
  const int gl = 3 * G;
  const size_t htab = (size_t)N * F * 2;   // bytes per head table
  const unsigned rowb = (unsigned)(F * 2); // bytes per row within a head table
  int o0 = off[n], d = off[n + 1] - o0;
  float er0 = erp[n * 4 + 0], er1 = erp[n * 4 + 1], er2 = erp[n * 4 + 2];
  const float4* elv = (const float4*)elp;
  const char* fb0 = (const char*)featb;
  int g = l / G; if (g > 2) g = 2;
  const int q = l % G;
  const unsigned loffs = (unsigned)q * 8u;
  const float4* plw = pl[wv];

  if (l < 4) pl[wv][64 + l] = make_float4(0.f, 0.f, 0.f, 0.f);

  float m0 = -1e30f, m1 = -1e30f, m2 = -1e30f;
  float s0 = 0.f, s1 = 0.f, s2 = 0.f;
  f32x4 acc0 = {0.f,0.f,0.f,0.f}, acc1 = {0.f,0.f,0.f,0.f}, acc2 = {0.f,0.f,0.f,0.f};

  for (int base = 0; base < d; base += 64) {
    int i = base + l;
    float x0 = -1e30f, x1 = -1e30f, x2 = -1e30f;
    unsigned boff = 0;
    if (i < d) {
      int ssrc = adj[o0 + i];
      boff = (unsigned)ssrc * rowb;
      float4 ev = elv[ssrc];
      x0 = ev.x + er0; x0 = fmaxf(x0, 0.2f * x0);
      x1 = ev.y + er1; x1 = fmaxf(x1, 0.2f * x1);
      x2 = ev.z + er2; x2 = fmaxf(x2, 0.2f * x2);
    }
    float c0 = x0, c1 = x1, c2 = x2;
    #pragma unroll
    for (int o_ = 32; o_ > 0; o_ >>= 1) {
      c0 = fmaxf(c0, __shfl_xor(c0, o_, 64));
      c1 = fmaxf(c1, __shfl_xor(c1, o_, 64));
      c2 = fmaxf(c2, __shfl_xor(c2, o_, 64));
    }
    float M0 = fmaxf(m0, c0), M1 = fmaxf(m1, c1), M2 = fmaxf(m2, c2);
    float rr0 = __expf(m0 - M0), rr1 = __expf(m1 - M1), rr2 = __expf(m2 - M2);
    s0 *= rr0; s1 *= rr1; s2 *= rr2;
    acc0 *= rr0; acc1 *= rr1; acc2 *= rr2;
    m0 = M0; m1 = M1; m2 = M2;
    float p0 = __expf(x0 - M0), p1 = __expf(x1 - M1), p2 = __expf(x2 - M2);
    s0 += p0; s1 += p1; s2 += p2;
    pl[wv][l] = make_float4(__uint_as_float(boff), p0, p1, p2);

    int cnt = min(64, d - base);

#define ITEM(H, ACC, AA) { \
      const uint2 uu = *(const uint2*)(hb + (__float_as_uint((AA).x) + loffs)); \
      float ww = (H) == 0 ? (AA).y : (H) == 1 ? (AA).z : (AA).w; \
      (ACC)[0] += ww * __uint_as_float(uu.x << 16); \
      (ACC)[1] += ww * __uint_as_float(uu.x & 0xffff0000u); \
      (ACC)[2] += ww * __uint_as_float(uu.y << 16); \
      (ACC)[3] += ww * __uint_as_float(uu.y & 0xffff0000u); }

#define SWEEP(H, ACC) { \
      const char* hb = fb0 + (size_t)(H) * htab; \
      int e0 = 0; \
      for (; e0 + 12 <= cnt; e0 += 12) { \
        float4 a0 = plw[e0 + g], a1 = plw[e0 + 3 + g]; \
        float4 a2 = plw[e0 + 6 + g], a3 = plw[e0 + 9 + g]; \
        ITEM(H, ACC, a0) ITEM(H, ACC, a1) ITEM(H, ACC, a2) ITEM(H, ACC, a3) \
      } \
      for (; e0 < cnt; e0 += 3) { \
        float4 a0 = plw[e0 + g]; \
        ITEM(H, ACC, a0) \
      } }

    SWEEP(0, acc0)
    SWEEP(1, acc1)
    SWEEP(2, acc2)
#undef SWEEP
#undef ITEM
  }

  s0 = wred_sum(s0); s1 = wred_sum(s1); s2 = wred_sum(s2);
  float i0 = s0 > 0.f ? 1.f / s0 : 0.f;
  float i1 = s1 > 0.f ? 1.f / s1 : 0.f;
  float i2 = s2 > 0.f ? 1.f / s2 : 0.f;

  if (l >= gl) {
    acc0 = (f32x4){0.f,0.f,0.f,0.f};
    acc1 = (f32x4){0.f,0.f,0.f,0.f};
    acc2 = (f32x4){0.f,0.f,0.f,0.f};
  }

  if (mode == 0) {
    // cross-group sum via xor (groups at l, l+16, l+32; lanes 48+ are zero)
    f32x4 K = {0.f,0.f,0.f,0.f};
#define COMB64(ACC, IH, H) { \
      f32x4 t = (ACC); \
      _Pragma("unroll") \
      for (int c = 0; c < 4; ++c) { \
        t[c] += __shfl_xor(t[c], 16, 64); \
        t[c] += __shfl_xor(t[c], 32, 64); \
      } \
      t *= (IH); \
      if ((l >> 4) == (H)) K = t; }
    COMB64(acc0, i0, 0)
    COMB64(acc1, i1, 1)
    COMB64(acc2, i2, 2)
#undef COMB64
    if (l < 48) {
      ushort4 o;
      o.x = f2bf(fmaxf(K[0], 0.f)); o.y = f2bf(fmaxf(K[1], 0.f));
      o.z = f2bf(fmaxf(K[2], 0.f)); o.w = f2bf(fmaxf(K[3], 0.f));
      *(ushort4*)((unsigned short*)outp + (size_t)(l >> 4) * N * 64 + (size_t)n * 64 + (l & 15) * 4) = o;
    }
  } else {
    const int q10 = l % 10;
    f32x4 K = {0.f,0.f,0.f,0.f};
#define COMB40(ACC, IH, H) { \
      f32x4 t; \
      _Pragma("unroll") \
      for (int c = 0; c < 4; ++c) \
        t[c] = __shfl((ACC)[c], q10, 64) + __shfl((ACC)[c], q10 + 10, 64) + __shfl((ACC)[c], q10 + 20, 64); \
      t *= (IH); \
      if (l >= 10 * (H) && l < 10 * (H) + 10) K = t; }
    COMB40(acc0, i0, 0)
    COMB40(acc1, i1, 1)
    COMB40(acc2, i2, 2)
#undef COMB40
    f32x4 o;
    #pragma unroll
    for (int c = 0; c < 4; ++c)
      o[c] = (__shfl(K[c], l, 64) + __shfl(K[c], l + 10, 64) + __shfl(K[c], l + 20, 64)) * (1.f / 3.f);
    if (l < 10) {
      float4 ov = make_float4(o[0], o[1], o[2], o[3]);
      *(float4*)((float*)outp + (size_t)n * 40 + l * 4) = ov;
    }
  }
}

extern "C" void kernel_launch(void* const* d_in, const int* in_sizes, int n_in,
                              void* d_out, int out_size, void* d_ws, size_t ws_size,
                              hipStream_t stream) {
  const float* x   = (const float*)d_in[0];
  const int*   src = (const int*)d_in[1];
  const int*   dst = (const int*)d_in[2];
  const float* W0  = (const float*)d_in[3];
  const float* al0 = (const float*)d_in[4];
  const float* ar0 = (const float*)d_in[5];
  const float* W1  = (const float*)d_in[6];
  const float* al1 = (const float*)d_in[7];
  const float* ar1 = (const float*)d_in[8];
  const float* W2  = (const float*)d_in[9];
  const float* al2 = (const float*)d_in[10];
  const float* ar2 = (const float*)d_in[11];
  const int N = NNODES;
  const int E = in_sizes[1];
  float* out = (float*)d_out;

  char* w = (char*)d_ws;
  unsigned short* xb    = (unsigned short*)w; w += (size_t)N * 256 * 2;  // 25.6MB
  unsigned short* featb = (unsigned short*)w; w += (size_t)N * 192 * 2;  // 19.2MB
  unsigned short* aggb  = (unsigned short*)w; w += (size_t)N * 192 * 2;  // 19.2MB
  unsigned short* Bf    = (unsigned short*)w; w += (size_t)128 * 1024;   // 128KB
  float* elp = (float*)w; w += (size_t)N * 4 * 4;
  float* erp = (float*)w; w += (size_t)N * 4 * 4;
  int* off   = (int*)w;  w += (size_t)(N + 1) * 4;
  int* adj   = (int*)w;  w += (size_t)E * 4;
  int* bcur  = (int*)w;  w += (size_t)NBUCK * 4;
  int* bbase = (int*)w;  w += (size_t)NBUCK * 4;
  uint2* ebuf = (uint2*)xb;   // alias: dead until cvt_bf16 runs

  // CSR build via bucket partition (all scatters L2-local)
  hipMemsetAsync(bcur, 0, (size_t)NBUCK * 4, stream);
  partition_kernel<<<(E + 2047) / 2048, 256, 0, stream>>>(src, dst, bcur, ebuf, E);
  bucket_scan_kernel<<<1, 256, 0, stream>>>(bcur, bbase);
  fill_local_kernel<<<NBUCK, 256, 0, stream>>>(ebuf, bcur, bbase, off, adj, N);

  // x -> bf16 (after CSR: xb aliases ebuf)
  cvt_bf16_kernel<<<(N * 256 / 4 + 255) / 256, 256, 0, stream>>>(x, xb, N * 256 / 4);

  int gblk = (N + 63) / 64;
  int ablk = (N + 3) / 4;
  unsigned long long HSh = (unsigned long long)N * 64;

  // layer 0: K=256, NT=13 (192 feat cols + tile12 = el/er), A node-major
  prep_b_kernel<<<(8 * 13 * 64 + 255) / 256, 256, 0, stream>>>(W0, al0, ar0, Bf, 256, 13, 192, 64);
  gemm_mfma_kernel<<<gblk, 256, 0, stream>>>(xb, Bf, featb, elp, erp, N, 256, 13, 192, 64ULL, 256, 64);
  aggregate_kernel<<<ablk, 256, 0, stream>>>(featb, adj, off, elp, erp, aggb, N, 64, 0);
  // layer 1: K=192, NT=13, A head-major
  prep_b_kernel<<<(6 * 13 * 64 + 255) / 256, 256, 0, stream>>>(W1, al1, ar1, Bf, 192, 13, 192, 64);
  gemm_mfma_kernel<<<gblk, 256, 0, stream>>>(aggb, Bf, featb, elp, erp, N, 192, 13, 192, HSh, 64, 64);
  aggregate_kernel<<<ablk, 256, 0, stream>>>(featb, adj, off, elp, erp, aggb, N, 64, 0);
  // layer 2: K=192, NT=8 (120 feat cols + el/er in tile 7), A head-major
  prep_b_kernel<<<(6 * 8 * 64 + 255) / 256, 256, 0, stream>>>(W2, al2, ar2, Bf, 192, 8, 120, 40);
  gemm_mfma_kernel<<<gblk, 256, 0, stream>>>(aggb, Bf, featb, elp, erp, N, 192, 8, 120, HSh, 64, 40);
  aggregate_kernel<<<ablk, 256, 0, stream>>>(featb, adj, off, elp, erp, out, N, 40, 1);
}

// Round 8
// 451.813 us; speedup vs baseline: 1.3629x; 1.3629x over previous
//
#include <hip/hip_runtime.h>

#define NNODES 50000
#define HEADS 3
#define NBUCK 196          // ceil(50000/256)
#define BCAP  16320        // per-bucket edge capacity (avg 8163)

typedef __attribute__((ext_vector_type(8))) short bf16x8;
typedef __attribute__((ext_vector_type(4))) float f32x4;

__device__ __forceinline__ float wred_sum(float v){
  #pragma unroll
  for (int s = 32; s > 0; s >>= 1) v += __shfl_xor(v, s, 64);
  return v;
}
__device__ __forceinline__ unsigned short f2bf(float x){
  unsigned int u = __float_as_uint(x);
  unsigned int r = (u + 0x7FFFu + ((u >> 16) & 1u)) >> 16;
  return (unsigned short)r;
}

// ---------------- W -> MFMA-fragment bf16, folded el/er cols; all 3 layers -
__global__ __launch_bounds__(256) void prep_b_all_kernel(
    const float* __restrict__ W0, const float* __restrict__ al0, const float* __restrict__ ar0,
    const float* __restrict__ W1, const float* __restrict__ al1, const float* __restrict__ ar1,
    const float* __restrict__ W2, const float* __restrict__ al2, const float* __restrict__ ar2,
    unsigned short* __restrict__ BfAll)
{
  const int layer = blockIdx.y;
  const float *W, *al, *ar;
  int K, NT, NCf, F; unsigned short* Bf;
  if (layer == 0) { W=W0; al=al0; ar=ar0; K=256; NT=13; NCf=192; F=64; Bf=BfAll; }
  else if (layer == 1) { W=W1; al=al1; ar=ar1; K=192; NT=13; NCf=192; F=64; Bf=BfAll+53248; }
  else { W=W2; al=al2; ar=ar2; K=192; NT=8; NCf=120; F=40; Bf=BfAll+93184; }

  int tid = blockIdx.x * 256 + threadIdx.x;
  int total = (K >> 5) * NT * 64;
  if (tid >= total) return;
  int l  = tid & 63;
  int t  = (tid >> 6) % NT;
  int kc = tid / (NT * 64);
  int k0  = kc * 32 + (l >> 4) * 8;
  int col = t * 16 + (l & 15);
  unsigned short o[8];
  #pragma unroll
  for (int j = 0; j < 8; ++j) {
    int k = k0 + j;
    float v = 0.f;
    if (col < NCf) {
      v = W[(size_t)k * NCf + col];
    } else if (col < NCf + 6) {
      int c = col - NCf;
      int h = (c < 3) ? c : c - 3;
      const float* av = ((c < 3) ? al : ar) + h * F;
      const float* wp = W + (size_t)k * NCf + h * F;
      float a = 0.f;
      for (int f = 0; f < F; ++f) a += wp[f] * av[f];
      v = a;
    }
    o[j] = f2bf(v);
  }
  ushort4* dst = (ushort4*)&Bf[(size_t)tid * 8];
  dst[0] = make_ushort4(o[0], o[1], o[2], o[3]);
  dst[1] = make_ushort4(o[4], o[5], o[6], o[7]);
}

// ---------------- MFMA GEMM + el/er epilogue ----------------
// AF32=1: A is fp32 [M][K], converted inline. AF32=0: A is bf16 [M][K].
template<int AF32>
__global__ __launch_bounds__(256) void gemm_mfma_kernel(
    const void* __restrict__ Ap, const unsigned short* __restrict__ Bf,
    unsigned short* __restrict__ Cb, float* __restrict__ elp, float* __restrict__ erp,
    int M, int K, int NT, int NCf)
{
  const int w = threadIdx.x >> 6, l = threadIdx.x & 63;
  const int lrow = l & 15, kg = l >> 4;
  const int r0 = blockIdx.x * 64;
  const bf16x8* Bfv = (const bf16x8*)Bf;

  f32x4 acc[4][4];
  #pragma unroll
  for (int mt = 0; mt < 4; ++mt)
    #pragma unroll
    for (int j = 0; j < 4; ++j)
      acc[mt][j] = (f32x4){0.f, 0.f, 0.f, 0.f};

  const int nkc = K >> 5;
  for (int kc = 0; kc < nkc; ++kc) {
    bf16x8 af[4];
    #pragma unroll
    for (int mt = 0; mt < 4; ++mt) {
      int row = r0 + mt * 16 + lrow;
      bf16x8 z = {0,0,0,0,0,0,0,0};
      af[mt] = z;
      if (row < M) {
        if (AF32) {
          const float* Af = (const float*)Ap;
          const float4 v0 = *(const float4*)&Af[(size_t)row * K + kc * 32 + kg * 8];
          const float4 v1 = *(const float4*)&Af[(size_t)row * K + kc * 32 + kg * 8 + 4];
          bf16x8 a;
          a[0] = (short)f2bf(v0.x); a[1] = (short)f2bf(v0.y);
          a[2] = (short)f2bf(v0.z); a[3] = (short)f2bf(v0.w);
          a[4] = (short)f2bf(v1.x); a[5] = (short)f2bf(v1.y);
          a[6] = (short)f2bf(v1.z); a[7] = (short)f2bf(v1.w);
          af[mt] = a;
        } else {
          const unsigned short* Ab = (const unsigned short*)Ap;
          af[mt] = *(const bf16x8*)&Ab[(size_t)row * K + kc * 32 + kg * 8];
        }
      }
    }
    #pragma unroll
    for (int j = 0; j < 4; ++j) {
      int tile = w + 4 * j;
      if (tile < NT) {
        bf16x8 bfr = Bfv[((size_t)kc * NT + tile) * 64 + l];
        #pragma unroll
        for (int mt = 0; mt < 4; ++mt)
          acc[mt][j] = __builtin_amdgcn_mfma_f32_16x16x32_bf16(af[mt], bfr, acc[mt][j], 0, 0, 0);
      }
    }
  }
  #pragma unroll
  for (int j = 0; j < 4; ++j) {
    int tile = w + 4 * j;
    if (tile >= NT) continue;
    int c = tile * 16 + lrow;
    #pragma unroll
    for (int mt = 0; mt < 4; ++mt) {
      #pragma unroll
      for (int rr = 0; rr < 4; ++rr) {
        int row = r0 + mt * 16 + kg * 4 + rr;
        if (row >= M) continue;
        float v = acc[mt][j][rr];
        if (c < NCf)            Cb[(size_t)row * NCf + c] = f2bf(v);
        else if (c < NCf + 3)   elp[row * 4 + (c - NCf)] = v;
        else if (c < NCf + 6)   erp[row * 4 + (c - NCf - 3)] = v;
      }
    }
  }
}

// ---------------- CSR build: bucket partition ----------------
__global__ __launch_bounds__(256) void partition_kernel(
    const int* __restrict__ src, const int* __restrict__ dst,
    int* __restrict__ bcur, uint2* __restrict__ ebuf, int E)
{
  __shared__ int hist[NBUCK];
  __shared__ int gbase[NBUCK];
  const int t = threadIdx.x;
  const int e0 = blockIdx.x * 2048;
  for (int i = t; i < NBUCK; i += 256) hist[i] = 0;
  __syncthreads();
  int  b_[8], r_[8];
  uint2 p_[8];
  #pragma unroll
  for (int v = 0; v < 8; ++v) {
    int e = e0 + v * 256 + t;
    b_[v] = -1;
    if (e < E) {
      int s = src[e], d = dst[e];
      p_[v] = make_uint2((unsigned)s, (unsigned)d);
      b_[v] = d >> 8;
      r_[v] = atomicAdd(&hist[b_[v]], 1);
    }
  }
  __syncthreads();
  for (int i = t; i < NBUCK; i += 256) {
    int h = hist[i];
    gbase[i] = h ? atomicAdd(&bcur[i], h) : 0;
  }
  __syncthreads();
  #pragma unroll
  for (int v = 0; v < 8; ++v)
    if (b_[v] >= 0)
      ebuf[(size_t)b_[v] * BCAP + gbase[b_[v]] + r_[v]] = p_[v];
}

// One WG per bucket; computes its own base via local prefix over bcur,
// builds off[] via LDS histogram+scan, then L2-local scatter into adj.
__global__ __launch_bounds__(256) void fill_local_kernel(
    const uint2* __restrict__ ebuf, const int* __restrict__ bcur,
    int* __restrict__ off, int* __restrict__ adj, int N)
{
  __shared__ int lhist[256], loff[256], lcur[256];
  __shared__ int wsum[4];
  __shared__ int sbase;
  const int b = blockIdx.x;
  const int t = threadIdx.x;
  const int wv = t >> 6, l = t & 63;
  const int cnt = bcur[b];
  const uint2* seg = ebuf + (size_t)b * BCAP;

  // base = exclusive prefix of bcur over buckets
  {
    int v = (t < NBUCK) ? bcur[t] : 0;
    int x = v;
    #pragma unroll
    for (int s = 1; s < 64; s <<= 1) {
      int y = __shfl_up(x, s, 64);
      if (l >= s) x += y;
    }
    if (l == 63) wsum[wv] = x;
    lhist[t] = 0; lcur[t] = 0;
    __syncthreads();
    int woff = 0;
    #pragma unroll
    for (int k = 0; k < 4; ++k) woff += (k < wv) ? wsum[k] : 0;
    if (t == b) sbase = woff + x - v;
  }
  __syncthreads();

  for (int i = t; i < cnt; i += 256)
    atomicAdd(&lhist[seg[i].y & 255], 1);
  __syncthreads();

  int v = lhist[t];
  int x = v;
  #pragma unroll
  for (int s = 1; s < 64; s <<= 1) {
    int y = __shfl_up(x, s, 64);
    if (l >= s) x += y;
  }
  if (l == 63) wsum[wv] = x;
  __syncthreads();
  int woff = 0;
  #pragma unroll
  for (int k = 0; k < 4; ++k) woff += (k < wv) ? wsum[k] : 0;
  loff[t] = woff + x - v;
  int gd = (b << 8) + t;
  if (gd <= N) off[gd] = sbase + loff[t];
  __syncthreads();
  const int base = sbase;
  for (int i = t; i < cnt; i += 256) {
    uint2 p = seg[i];
    int d = p.y & 255;
    int r = atomicAdd(&lcur[d], 1);
    adj[base + loff[d] + r] = (int)p.x;
  }
}

// ---------------- aggregation: one wave per dst node ----------
// Softmax without max-subtraction (shift-invariant; args bounded ~|12| so
// fp32 exp is safe). One pass: p=exp(leaky(el+er)), s+=p, gather w*feat.
// mode 0: F=64, out = relu(agg) -> bf16 [N,192]
// mode 1: F=40, out = mean over heads -> fp32 [N,40]
__global__ __launch_bounds__(256) void aggregate_kernel(
    const unsigned short* __restrict__ featb, const int* __restrict__ adj,
    const int* __restrict__ off, const float* __restrict__ elp,
    const float* __restrict__ erp, void* __restrict__ outp,
    int N, int F, int mode)
{
  __shared__ float4 pl[4][64];
  int wv = threadIdx.x >> 6, l = threadIdx.x & 63;
  int n  = blockIdx.x * 4 + wv;
  if (n >= N) return;
  const int NC = HEADS * F;
  const unsigned rowbytes = NC * 2;
  int o0 = off[n], d = off[n + 1] - o0;
  float er0 = erp[n * 4 + 0], er1 = erp[n * 4 + 1], er2 = erp[n * 4 + 2];
  const float4* elv = (const float4*)elp;
  const char* fbase = (const char*)featb;
  const int gl = (F == 64) ? 48 : 30;
  const int h  = (F == 64) ? (l >> 4) : (l / 10);
  const unsigned loff2 = (unsigned)l * 8u;
  const float4* plw = pl[wv];

  float s0 = 0.f, s1 = 0.f, s2 = 0.f;
  float4 acc = {0.f, 0.f, 0.f, 0.f};

  for (int base = 0; base < d; base += 64) {
    int i = base + l;
    float p0 = 0.f, p1 = 0.f, p2 = 0.f;
    unsigned boff = 0;
    if (i < d) {
      int ssrc = adj[o0 + i];
      boff = (unsigned)ssrc * rowbytes;
      float4 ev = elv[ssrc];
      float x0 = ev.x + er0; x0 = fmaxf(x0, 0.2f * x0);
      float x1 = ev.y + er1; x1 = fmaxf(x1, 0.2f * x1);
      float x2 = ev.z + er2; x2 = fmaxf(x2, 0.2f * x2);
      p0 = __expf(x0); p1 = __expf(x1); p2 = __expf(x2);
    }
    s0 += p0; s1 += p1; s2 += p2;
    pl[wv][l] = make_float4(__uint_as_float(boff), p0, p1, p2);

    int cnt = min(64, d - base);
    if (l < gl) {
      int e = 0;
      for (; e + 4 <= cnt; e += 4) {
        float4 a0 = plw[e], a1 = plw[e + 1], a2 = plw[e + 2], a3 = plw[e + 3];
        uint2 u0 = *(const uint2*)(fbase + (__float_as_uint(a0.x) + loff2));
        uint2 u1 = *(const uint2*)(fbase + (__float_as_uint(a1.x) + loff2));
        uint2 u2 = *(const uint2*)(fbase + (__float_as_uint(a2.x) + loff2));
        uint2 u3 = *(const uint2*)(fbase + (__float_as_uint(a3.x) + loff2));
        float w0 = (h == 0) ? a0.y : (h == 1) ? a0.z : a0.w;
        float w1 = (h == 0) ? a1.y : (h == 1) ? a1.z : a1.w;
        float w2 = (h == 0) ? a2.y : (h == 1) ? a2.z : a2.w;
        float w3 = (h == 0) ? a3.y : (h == 1) ? a3.z : a3.w;
        acc.x += w0 * __uint_as_float(u0.x << 16);
        acc.y += w0 * __uint_as_float(u0.x & 0xffff0000u);
        acc.z += w0 * __uint_as_float(u0.y << 16);
        acc.w += w0 * __uint_as_float(u0.y & 0xffff0000u);
        acc.x += w1 * __uint_as_float(u1.x << 16);
        acc.y += w1 * __uint_as_float(u1.x & 0xffff0000u);
        acc.z += w1 * __uint_as_float(u1.y << 16);
        acc.w += w1 * __uint_as_float(u1.y & 0xffff0000u);
        acc.x += w2 * __uint_as_float(u2.x << 16);
        acc.y += w2 * __uint_as_float(u2.x & 0xffff0000u);
        acc.z += w2 * __uint_as_float(u2.y << 16);
        acc.w += w2 * __uint_as_float(u2.y & 0xffff0000u);
        acc.x += w3 * __uint_as_float(u3.x << 16);
        acc.y += w3 * __uint_as_float(u3.x & 0xffff0000u);
        acc.z += w3 * __uint_as_float(u3.y << 16);
        acc.w += w3 * __uint_as_float(u3.y & 0xffff0000u);
      }
      for (; e < cnt; ++e) {
        float4 a0 = plw[e];
        uint2 u0 = *(const uint2*)(fbase + (__float_as_uint(a0.x) + loff2));
        float w0 = (h == 0) ? a0.y : (h == 1) ? a0.z : a0.w;
        acc.x += w0 * __uint_as_float(u0.x << 16);
        acc.y += w0 * __uint_as_float(u0.x & 0xffff0000u);
        acc.z += w0 * __uint_as_float(u0.y << 16);
        acc.w += w0 * __uint_as_float(u0.y & 0xffff0000u);
      }
    }
  }

  s0 = wred_sum(s0); s1 = wred_sum(s1); s2 = wred_sum(s2);
  float i0 = s0 > 0.f ? 1.f / s0 : 0.f;
  float i1 = s1 > 0.f ? 1.f / s1 : 0.f;
  float i2 = s2 > 0.f ? 1.f / s2 : 0.f;
  float ih = (h == 0) ? i0 : (h == 1) ? i1 : i2;
  acc.x *= ih; acc.y *= ih; acc.z *= ih; acc.w *= ih;

  if (mode == 0) {
    if (l < 48) {
      ushort4 o;
      o.x = f2bf(fmaxf(acc.x, 0.f)); o.y = f2bf(fmaxf(acc.y, 0.f));
      o.z = f2bf(fmaxf(acc.z, 0.f)); o.w = f2bf(fmaxf(acc.w, 0.f));
      *(ushort4*)((unsigned short*)outp + (size_t)n * 192 + l * 4) = o;
    }
  } else {
    float bx = __shfl(acc.x, l + 10, 64), cx = __shfl(acc.x, l + 20, 64);
    float by = __shfl(acc.y, l + 10, 64), cy = __shfl(acc.y, l + 20, 64);
    float bz = __shfl(acc.z, l + 10, 64), cz = __shfl(acc.z, l + 20, 64);
    float bw = __shfl(acc.w, l + 10, 64), cw = __shfl(acc.w, l + 20, 64);
    if (l < 10) {
      float4 o;
      o.x = (acc.x + bx + cx) * (1.f / 3.f);
      o.y = (acc.y + by + cy) * (1.f / 3.f);
      o.z = (acc.z + bz + cz) * (1.f / 3.f);
      o.w = (acc.w + bw + cw) * (1.f / 3.f);
      *(float4*)((float*)outp + (size_t)n * 40 + l * 4) = o;
    }
  }
}

extern "C" void kernel_launch(void* const* d_in, const int* in_sizes, int n_in,
                              void* d_out, int out_size, void* d_ws, size_t ws_size,
                              hipStream_t stream) {
  const float* x   = (const float*)d_in[0];
  const int*   src = (const int*)d_in[1];
  const int*   dst = (const int*)d_in[2];
  const float* W0  = (const float*)d_in[3];
  const float* al0 = (const float*)d_in[4];
  const float* ar0 = (const float*)d_in[5];
  const float* W1  = (const float*)d_in[6];
  const float* al1 = (const float*)d_in[7];
  const float* ar1 = (const float*)d_in[8];
  const float* W2  = (const float*)d_in[9];
  const float* al2 = (const float*)d_in[10];
  const float* ar2 = (const float*)d_in[11];
  const int N = NNODES;
  const int E = in_sizes[1];
  float* out = (float*)d_out;

  char* w = (char*)d_ws;
  uint2*          ebuf  = (uint2*)w;          w += (size_t)NBUCK * BCAP * 8; // 25.6MB
  unsigned short* featb = (unsigned short*)w; w += (size_t)N * 192 * 2;      // 19.2MB
  unsigned short* aggb  = (unsigned short*)w; w += (size_t)N * 192 * 2;      // 19.2MB
  unsigned short* Bf    = (unsigned short*)w; w += (size_t)256 * 1024;       // 256KB
  float* elp = (float*)w; w += (size_t)N * 4 * 4;
  float* erp = (float*)w; w += (size_t)N * 4 * 4;
  int* off   = (int*)w;  w += (size_t)(N + 1) * 4;
  int* adj   = (int*)w;  w += (size_t)E * 4;
  int* bcur  = (int*)w;  w += (size_t)NBUCK * 4;

  // CSR build via bucket partition (all scatters L2-local)
  hipMemsetAsync(bcur, 0, (size_t)NBUCK * 4, stream);
  partition_kernel<<<(E + 2047) / 2048, 256, 0, stream>>>(src, dst, bcur, ebuf, E);
  fill_local_kernel<<<NBUCK, 256, 0, stream>>>(ebuf, bcur, off, adj, N);

  // all weight prep in one launch (26 blocks x 3 layers)
  prep_b_all_kernel<<<dim3(26, 3), 256, 0, stream>>>(W0, al0, ar0, W1, al1, ar1,
                                                     W2, al2, ar2, Bf);

  int gblk = (N + 63) / 64;
  int ablk = (N + 3) / 4;

  // layer 0: fp32 A converted inline; K=256, NT=13 (192 feat + el/er tile)
  gemm_mfma_kernel<1><<<gblk, 256, 0, stream>>>(x, Bf, featb, elp, erp, N, 256, 13, 192);
  aggregate_kernel<<<ablk, 256, 0, stream>>>(featb, adj, off, elp, erp, aggb, N, 64, 0);
  // layer 1: K=192, NT=13
  gemm_mfma_kernel<0><<<gblk, 256, 0, stream>>>(aggb, Bf + 53248, featb, elp, erp, N, 192, 13, 192);
  aggregate_kernel<<<ablk, 256, 0, stream>>>(featb, adj, off, elp, erp, aggb, N, 64, 0);
  // layer 2: K=192, NT=8 (120 feat cols + el/er in tile 7)
  gemm_mfma_kernel<0><<<gblk, 256, 0, stream>>>(aggb, Bf + 93184, featb, elp, erp, N, 192, 8, 120);
  aggregate_kernel<<<ablk, 256, 0, stream>>>(featb, adj, off, elp, erp, out, N, 40, 1);
}